// Round 10
// baseline (14787.805 us; speedup 1.0000x reference)
//
#include <hip/hip_runtime.h>
#include <hip/hip_bf16.h>
#include <math.h>

#define RR 374
#define FF 128
#define NBT 576
#define KSEL 299
#define PROBN (NBT * RR)   // 215424
#define NT 6               // 64-row tiles per (b,t)

__device__ __forceinline__ float gelu_f(float v) {
    return 0.5f * v * (1.f + erff(v * 0.70710678118654752f));
}

__device__ __forceinline__ void fma4(float4& d, float s, const float4 w) {
    d.x = fmaf(s, w.x, d.x);
    d.y = fmaf(s, w.y, d.y);
    d.z = fmaf(s, w.z, d.z);
    d.w = fmaf(s, w.w, d.w);
}

// 64-lane sum via DPP (row_shr scan + row bcasts), result uniform via readlane.
__device__ __forceinline__ float wsum64(float v) {
    v += __int_as_float(__builtin_amdgcn_update_dpp(0, __float_as_int(v), 0x111, 0xf, 0xf, true));
    v += __int_as_float(__builtin_amdgcn_update_dpp(0, __float_as_int(v), 0x112, 0xf, 0xf, true));
    v += __int_as_float(__builtin_amdgcn_update_dpp(0, __float_as_int(v), 0x114, 0xf, 0xf, true));
    v += __int_as_float(__builtin_amdgcn_update_dpp(0, __float_as_int(v), 0x118, 0xf, 0xf, true));
    v += __int_as_float(__builtin_amdgcn_update_dpp(0, __float_as_int(v), 0x142, 0xa, 0xf, true));
    v += __int_as_float(__builtin_amdgcn_update_dpp(0, __float_as_int(v), 0x143, 0xc, 0xf, true));
    return __int_as_float(__builtin_amdgcn_readlane(__float_as_int(v), 63));
}

// Two independent 64-lane sums, chains interleaved for ILP.
__device__ __forceinline__ void wsum64x2(float& a, float& b) {
    a += __int_as_float(__builtin_amdgcn_update_dpp(0, __float_as_int(a), 0x111, 0xf, 0xf, true));
    b += __int_as_float(__builtin_amdgcn_update_dpp(0, __float_as_int(b), 0x111, 0xf, 0xf, true));
    a += __int_as_float(__builtin_amdgcn_update_dpp(0, __float_as_int(a), 0x112, 0xf, 0xf, true));
    b += __int_as_float(__builtin_amdgcn_update_dpp(0, __float_as_int(b), 0x112, 0xf, 0xf, true));
    a += __int_as_float(__builtin_amdgcn_update_dpp(0, __float_as_int(a), 0x114, 0xf, 0xf, true));
    b += __int_as_float(__builtin_amdgcn_update_dpp(0, __float_as_int(b), 0x114, 0xf, 0xf, true));
    a += __int_as_float(__builtin_amdgcn_update_dpp(0, __float_as_int(a), 0x118, 0xf, 0xf, true));
    b += __int_as_float(__builtin_amdgcn_update_dpp(0, __float_as_int(b), 0x118, 0xf, 0xf, true));
    a += __int_as_float(__builtin_amdgcn_update_dpp(0, __float_as_int(a), 0x142, 0xa, 0xf, true));
    b += __int_as_float(__builtin_amdgcn_update_dpp(0, __float_as_int(b), 0x142, 0xa, 0xf, true));
    a += __int_as_float(__builtin_amdgcn_update_dpp(0, __float_as_int(a), 0x143, 0xc, 0xf, true));
    b += __int_as_float(__builtin_amdgcn_update_dpp(0, __float_as_int(b), 0x143, 0xc, 0xf, true));
    a = __int_as_float(__builtin_amdgcn_readlane(__float_as_int(a), 63));
    b = __int_as_float(__builtin_amdgcn_readlane(__float_as_int(b), 63));
}

// ===========================================================================
// K1: (bt, tile64) -> LN(64 rows) -> GEMM1, software-pipelined w1 prefetch.
// Thread = 4 rows x (4 lo + 4 hi) cols. FMA order identical to Round 9.
// ===========================================================================
#define LOADW4(P, KB) \
    P##l0 = *(const float4*)(wp + (KB + 0) * 128); P##h0 = *(const float4*)(wp + (KB + 0) * 128 + 64); \
    P##l1 = *(const float4*)(wp + (KB + 1) * 128); P##h1 = *(const float4*)(wp + (KB + 1) * 128 + 64); \
    P##l2 = *(const float4*)(wp + (KB + 2) * 128); P##h2 = *(const float4*)(wp + (KB + 2) * 128 + 64); \
    P##l3 = *(const float4*)(wp + (KB + 3) * 128); P##h3 = *(const float4*)(wp + (KB + 3) * 128 + 64);

#define ACC8(WL, WH, S0, S1, S2, S3) \
    fma4(acL[0], S0, WL); fma4(acH[0], S0, WH); \
    fma4(acL[1], S1, WL); fma4(acH[1], S1, WH); \
    fma4(acL[2], S2, WL); fma4(acH[2], S2, WH); \
    fma4(acL[3], S3, WL); fma4(acH[3], S3, WH);

#define COMPUTE4(P, KB) { \
    const float4 x0 = *(const float4*)&xn[(r0l + 0) * 132 + (KB)]; \
    const float4 x1 = *(const float4*)&xn[(r0l + 1) * 132 + (KB)]; \
    const float4 x2 = *(const float4*)&xn[(r0l + 2) * 132 + (KB)]; \
    const float4 x3 = *(const float4*)&xn[(r0l + 3) * 132 + (KB)]; \
    ACC8(P##l0, P##h0, x0.x, x1.x, x2.x, x3.x); \
    ACC8(P##l1, P##h1, x0.y, x1.y, x2.y, x3.y); \
    ACC8(P##l2, P##h2, x0.z, x1.z, x2.z, x3.z); \
    ACC8(P##l3, P##h3, x0.w, x1.w, x2.w, x3.w); }

__global__ __launch_bounds__(256, 3) void k_gemm1(
    const float* __restrict__ x,
    const float* __restrict__ ln_w, const float* __restrict__ ln_b,
    const float* __restrict__ w1, const float* __restrict__ b1,
    float* __restrict__ localo, float* __restrict__ parto)
{
    __shared__ __align__(16) float xn[64 * 132];   // 33.8 KB
    __shared__ float part[16 * 64];                // 4 KB

    const int blk   = blockIdx.x;
    const int bt    = blk / NT;
    const int tile  = blk - bt * NT;
    const int rows0 = tile * 64;
    const int tid   = threadIdx.x;
    const int lane  = tid & 63;
    const int wv    = tid >> 6;
    const int cg    = tid & 15;
    const int rg    = tid >> 4;

    const float* xbt = x + (size_t)bt * RR * FF;

    // ---- LayerNorm 64 rows (zeros beyond RR), DPP reductions ----
    for (int rl = wv; rl < 64; rl += 4) {
        const int r = rows0 + rl;
        float2 v = make_float2(0.f, 0.f);
        if (r < RR) v = *(const float2*)&xbt[r * FF + 2 * lane];
        const float m = wsum64(v.x + v.y) * (1.f / 128.f);
        const float dx = v.x - m, dy = v.y - m;
        const float var = wsum64(dx * dx + dy * dy) * (1.f / 128.f);
        const float rstd = 1.f / sqrtf(var + 1e-5f);
        const float2 lw = *(const float2*)&ln_w[2 * lane];
        const float2 lb = *(const float2*)&ln_b[2 * lane];
        float2 o2;
        o2.x = dx * rstd * lw.x + lb.x;
        o2.y = dy * rstd * lw.y + lb.y;
        *(float2*)&xn[rl * 132 + 2 * lane] = o2;
    }
    __syncthreads();

    // ---- GEMM with 2-deep prefetch pipeline (A/B 4-k-slice buffers) ----
    float4 acL[4] = {{0,0,0,0},{0,0,0,0},{0,0,0,0},{0,0,0,0}};
    float4 acH[4] = {{0,0,0,0},{0,0,0,0},{0,0,0,0},{0,0,0,0}};
    const int r0l = 4 * rg;
    const float* wp = w1 + 4 * cg;

    float4 Al0, Ah0, Al1, Ah1, Al2, Ah2, Al3, Ah3;
    float4 Bl0, Bh0, Bl1, Bh1, Bl2, Bh2, Bl3, Bh3;

    LOADW4(A, 0);
    #pragma unroll
    for (int k = 0; k < 128; k += 8) {
        LOADW4(B, k + 4);
        COMPUTE4(A, k);
        if (k + 8 < 128) { LOADW4(A, k + 8); }
        COMPUTE4(B, k + 4);
    }

    // ---- epilogue ----
    const float4 bl = *(const float4*)&b1[4 * cg];
    const float4 bh = *(const float4*)&b1[64 + 4 * cg];
    float hs0 = 0.f, hs1 = 0.f, hs2 = 0.f, hs3 = 0.f;
    #pragma unroll
    for (int i = 0; i < 4; ++i) {
        const int r = rows0 + r0l + i;
        if (r < RR) {
            float4 g;
            g.x = gelu_f(acL[i].x + bl.x);
            g.y = gelu_f(acL[i].y + bl.y);
            g.z = gelu_f(acL[i].z + bl.z);
            g.w = gelu_f(acL[i].w + bl.w);
            *(float4*)&localo[((size_t)bt * RR + r) * 64 + 4 * cg] = g;
            hs0 += gelu_f(acH[i].x + bh.x);
            hs1 += gelu_f(acH[i].y + bh.y);
            hs2 += gelu_f(acH[i].z + bh.z);
            hs3 += gelu_f(acH[i].w + bh.w);
        }
    }
    part[rg * 64 + 4 * cg + 0] = hs0;
    part[rg * 64 + 4 * cg + 1] = hs1;
    part[rg * 64 + 4 * cg + 2] = hs2;
    part[rg * 64 + 4 * cg + 3] = hs3;
    __syncthreads();
    if (tid < 64) {
        float s = 0.f;
        #pragma unroll
        for (int g = 0; g < 16; ++g) s += part[g * 64 + tid];
        parto[((size_t)bt * NT + tile) * 64 + tid] = s;
    }
}

// ===========================================================================
// K2: per bt: glob mean -> gvec = b2 + glob . w2[64:,:]
// ===========================================================================
__global__ __launch_bounds__(64) void k_gvec(
    const float* __restrict__ parto, const float* __restrict__ w2,
    const float* __restrict__ b2, float* __restrict__ gvec_o)
{
    __shared__ float glob[64];
    const int bt  = blockIdx.x;
    const int tid = threadIdx.x;
    {
        float s = 0.f;
        #pragma unroll
        for (int t = 0; t < NT; ++t) s += parto[((size_t)bt * NT + t) * 64 + tid];
        glob[tid] = s / 374.f;
    }
    __syncthreads();
    if (tid < 32) {
        float a = b2[tid];
        for (int c = 0; c < 64; ++c)
            a = fmaf(glob[c], w2[(64 + c) * 32 + tid], a);
        gvec_o[bt * 32 + tid] = a;
    }
}

// ===========================================================================
// K3: (bt, tile32): GEMM2 -> GeLU -> GEMM3 -> softmax -> score+gumbel -> s0
// ===========================================================================
__global__ __launch_bounds__(256, 4) void k_score(
    const float* __restrict__ localo, const float* __restrict__ gvec_i,
    const float* __restrict__ w2, const float* __restrict__ w3,
    const float* __restrict__ b3, const float* __restrict__ u,
    float* __restrict__ s0out)
{
    __shared__ __align__(16) float w2s[64 * 32];   // 8 KB (lo half)
    __shared__ __align__(16) float lt[32 * 68];    // 8.7 KB
    __shared__ __align__(16) float gv[32];

    const int blk   = blockIdx.x;
    const int bt    = blk / 12;
    const int tile  = blk - bt * 12;
    const int rows0 = tile * 32;
    const int tid   = threadIdx.x;

    for (int i = tid; i < 512; i += 256)
        ((float4*)w2s)[i] = ((const float4*)w2)[i];
    if (tid < 32) gv[tid] = gvec_i[bt * 32 + tid];
    for (int i = tid; i < 512; i += 256) {
        const int r = i >> 4, c4 = i & 15;
        float4 v = {0.f, 0.f, 0.f, 0.f};
        if (rows0 + r < RR)
            v = *(const float4*)&localo[((size_t)bt * RR + rows0 + r) * 64 + 4 * c4];
        *(float4*)&lt[r * 68 + 4 * c4] = v;
    }
    __syncthreads();

    const int row = tid >> 3;
    const int jg  = tid & 7;
    const int r   = rows0 + row;
    float4 h2 = *(const float4*)&gv[4 * jg];
    const float* lrow = &lt[row * 68];
    #pragma unroll 8
    for (int c = 0; c < 64; ++c)
        fma4(h2, lrow[c], *(const float4*)&w2s[c * 32 + 4 * jg]);

    float pl0 = 0.f, pl1 = 0.f;
    #pragma unroll
    for (int jj = 0; jj < 4; ++jj) {
        const int j = 4 * jg + jj;
        const float hv = jj == 0 ? h2.x : (jj == 1 ? h2.y : (jj == 2 ? h2.z : h2.w));
        const float ge = gelu_f(hv);
        pl0 = fmaf(ge, w3[2 * j + 0], pl0);
        pl1 = fmaf(ge, w3[2 * j + 1], pl1);
    }
    pl0 += __shfl_xor(pl0, 1); pl0 += __shfl_xor(pl0, 2); pl0 += __shfl_xor(pl0, 4);
    pl1 += __shfl_xor(pl1, 1); pl1 += __shfl_xor(pl1, 2); pl1 += __shfl_xor(pl1, 4);
    if (jg == 0 && r < RR) {
        const float l0 = pl0 + b3[0];
        const float l1 = pl1 + b3[1];
        const float m3 = fmaxf(l0, l1);
        const float e0 = expf(l0 - m3);
        const float e1 = expf(l1 - m3);
        const float sc = e1 / (e0 + e1);
        const float uu = u[(size_t)bt * RR + r];
        const float gmb = -logf(-logf(uu));
        s0out[(size_t)bt * RR + r] = sc + gmb;
    }
}

// ===========================================================================
// FALLBACK: monolithic front (Round-6 proven), used only if ws too small
// ===========================================================================
__global__ __launch_bounds__(256) void k_front(
    const float* __restrict__ x, const float* __restrict__ u,
    const float* __restrict__ ln_w, const float* __restrict__ ln_b,
    const float* __restrict__ w1, const float* __restrict__ b1,
    const float* __restrict__ w2, const float* __restrict__ b2,
    const float* __restrict__ w3, const float* __restrict__ b3,
    float* __restrict__ s0out)
{
    __shared__ __align__(16) float Whalf[128 * 64];
    __shared__ __align__(16) float xn[32 * 132];
    __shared__ __align__(16) float ltile[32 * 68];
    __shared__ __align__(16) float w2s[128 * 32];
    __shared__ __align__(16) float part[16 * 64];
    __shared__ __align__(16) float globv[64];
    __shared__ __align__(16) float gvec[32];

    const int bt   = blockIdx.x;
    const int tid  = threadIdx.x;
    const int lane = tid & 63;
    const int wv   = tid >> 6;
    const int cg   = tid & 15;
    const int rg   = tid >> 4;

    const float* xbt = x + (size_t)bt * RR * FF;

    for (int i = tid; i < 128 * 32; i += 256) w2s[i] = w2[i];
    for (int i = tid; i < 128 * 64; i += 256)
        Whalf[i] = w1[(i >> 6) * 128 + 64 + (i & 63)];
    __syncthreads();

    float ups[4] = {0.f, 0.f, 0.f, 0.f};
    for (int tile = 0; tile < 12; ++tile) {
        const int rows0 = tile * 32;
        for (int rl = wv; rl < 32; rl += 4) {
            const int r = rows0 + rl;
            float2 v = make_float2(0.f, 0.f);
            if (r < RR) v = *(const float2*)&xbt[r * FF + 2 * lane];
            const float m = wsum64(v.x + v.y) * (1.f / 128.f);
            const float dx = v.x - m, dy = v.y - m;
            const float var = wsum64(dx * dx + dy * dy) * (1.f / 128.f);
            const float rstd = 1.f / sqrtf(var + 1e-5f);
            const float2 lw = *(const float2*)&ln_w[2 * lane];
            const float2 lb = *(const float2*)&ln_b[2 * lane];
            float2 o2;
            o2.x = dx * rstd * lw.x + lb.x;
            o2.y = dy * rstd * lw.y + lb.y;
            *(float2*)&xn[rl * 132 + 2 * lane] = o2;
        }
        __syncthreads();

        float4 a0 = {0, 0, 0, 0}, a1 = {0, 0, 0, 0};
        const int r0l = 2 * rg;
        const float* xr0 = &xn[r0l * 132];
        const float* xr1 = xr0 + 132;
        #pragma unroll 4
        for (int k = 0; k < 128; k += 4) {
            const float4 v0 = *(const float4*)(xr0 + k);
            const float4 v1 = *(const float4*)(xr1 + k);
            #pragma unroll
            for (int kk = 0; kk < 4; ++kk) {
                const float s0k = kk == 0 ? v0.x : (kk == 1 ? v0.y : (kk == 2 ? v0.z : v0.w));
                const float s1k = kk == 0 ? v1.x : (kk == 1 ? v1.y : (kk == 2 ? v1.z : v1.w));
                const float4 wvv = *(const float4*)&Whalf[(k + kk) * 64 + 4 * cg];
                fma4(a0, s0k, wvv);
                fma4(a1, s1k, wvv);
            }
        }
        if (rows0 + r0l < RR) {
            ups[0] += gelu_f(a0.x + b1[64 + 4 * cg + 0]);
            ups[1] += gelu_f(a0.y + b1[64 + 4 * cg + 1]);
            ups[2] += gelu_f(a0.z + b1[64 + 4 * cg + 2]);
            ups[3] += gelu_f(a0.w + b1[64 + 4 * cg + 3]);
        }
        if (rows0 + r0l + 1 < RR) {
            ups[0] += gelu_f(a1.x + b1[64 + 4 * cg + 0]);
            ups[1] += gelu_f(a1.y + b1[64 + 4 * cg + 1]);
            ups[2] += gelu_f(a1.z + b1[64 + 4 * cg + 2]);
            ups[3] += gelu_f(a1.w + b1[64 + 4 * cg + 3]);
        }
        __syncthreads();
    }

    #pragma unroll
    for (int c = 0; c < 4; ++c) part[rg * 64 + 4 * cg + c] = ups[c];
    __syncthreads();
    if (tid < 64) {
        float s = 0.f;
        for (int g = 0; g < 16; ++g) s += part[g * 64 + tid];
        globv[tid] = s / 374.f;
    }
    __syncthreads();
    if (tid < 32) {
        float a = b2[tid];
        for (int c = 0; c < 64; ++c)
            a = fmaf(globv[c], w2s[(64 + c) * 32 + tid], a);
        gvec[tid] = a;
    }
    __syncthreads();

    for (int i = tid; i < 128 * 64; i += 256)
        Whalf[i] = w1[(i >> 6) * 128 + (i & 63)];
    __syncthreads();

    for (int tile = 0; tile < 12; ++tile) {
        const int rows0 = tile * 32;
        for (int rl = wv; rl < 32; rl += 4) {
            const int r = rows0 + rl;
            float2 v = make_float2(0.f, 0.f);
            if (r < RR) v = *(const float2*)&xbt[r * FF + 2 * lane];
            const float m = wsum64(v.x + v.y) * (1.f / 128.f);
            const float dx = v.x - m, dy = v.y - m;
            const float var = wsum64(dx * dx + dy * dy) * (1.f / 128.f);
            const float rstd = 1.f / sqrtf(var + 1e-5f);
            const float2 lw = *(const float2*)&ln_w[2 * lane];
            const float2 lb = *(const float2*)&ln_b[2 * lane];
            float2 o2;
            o2.x = dx * rstd * lw.x + lb.x;
            o2.y = dy * rstd * lw.y + lb.y;
            *(float2*)&xn[rl * 132 + 2 * lane] = o2;
        }
        __syncthreads();

        float4 a0 = {0, 0, 0, 0}, a1 = {0, 0, 0, 0};
        const int r0l = 2 * rg;
        const float* xr0 = &xn[r0l * 132];
        const float* xr1 = xr0 + 132;
        #pragma unroll 4
        for (int k = 0; k < 128; k += 4) {
            const float4 v0 = *(const float4*)(xr0 + k);
            const float4 v1 = *(const float4*)(xr1 + k);
            #pragma unroll
            for (int kk = 0; kk < 4; ++kk) {
                const float s0k = kk == 0 ? v0.x : (kk == 1 ? v0.y : (kk == 2 ? v0.z : v0.w));
                const float s1k = kk == 0 ? v1.x : (kk == 1 ? v1.y : (kk == 2 ? v1.z : v1.w));
                const float4 wvv = *(const float4*)&Whalf[(k + kk) * 64 + 4 * cg];
                fma4(a0, s0k, wvv);
                fma4(a1, s1k, wvv);
            }
        }
        ltile[(r0l + 0) * 68 + 4 * cg + 0] = gelu_f(a0.x + b1[4 * cg + 0]);
        ltile[(r0l + 0) * 68 + 4 * cg + 1] = gelu_f(a0.y + b1[4 * cg + 1]);
        ltile[(r0l + 0) * 68 + 4 * cg + 2] = gelu_f(a0.z + b1[4 * cg + 2]);
        ltile[(r0l + 0) * 68 + 4 * cg + 3] = gelu_f(a0.w + b1[4 * cg + 3]);
        ltile[(r0l + 1) * 68 + 4 * cg + 0] = gelu_f(a1.x + b1[4 * cg + 0]);
        ltile[(r0l + 1) * 68 + 4 * cg + 1] = gelu_f(a1.y + b1[4 * cg + 1]);
        ltile[(r0l + 1) * 68 + 4 * cg + 2] = gelu_f(a1.z + b1[4 * cg + 2]);
        ltile[(r0l + 1) * 68 + 4 * cg + 3] = gelu_f(a1.w + b1[4 * cg + 3]);
        __syncthreads();

        {
            const int row = tid >> 3;
            const int jg  = tid & 7;
            const int r   = rows0 + row;
            float4 h2 = *(const float4*)&gvec[4 * jg];
            const float* lrow = &ltile[row * 68];
            #pragma unroll 8
            for (int c = 0; c < 64; ++c) {
                const float lv = lrow[c];
                const float4 wvv = *(const float4*)&w2s[c * 32 + 4 * jg];
                fma4(h2, lv, wvv);
            }
            float pl0 = 0.f, pl1 = 0.f;
            #pragma unroll
            for (int jj = 0; jj < 4; ++jj) {
                const int j = 4 * jg + jj;
                const float hv = jj == 0 ? h2.x : (jj == 1 ? h2.y : (jj == 2 ? h2.z : h2.w));
                const float ge = gelu_f(hv);
                pl0 = fmaf(ge, w3[2 * j + 0], pl0);
                pl1 = fmaf(ge, w3[2 * j + 1], pl1);
            }
            pl0 += __shfl_xor(pl0, 1); pl0 += __shfl_xor(pl0, 2); pl0 += __shfl_xor(pl0, 4);
            pl1 += __shfl_xor(pl1, 1); pl1 += __shfl_xor(pl1, 2); pl1 += __shfl_xor(pl1, 4);
            if (jg == 0 && r < RR) {
                const float l0 = pl0 + b3[0];
                const float l1 = pl1 + b3[1];
                const float m3 = fmaxf(l0, l1);
                const float e0 = expf(l0 - m3);
                const float e1 = expf(l1 - m3);
                const float sc = e1 / (e0 + e1);
                const float uu = u[(size_t)bt * RR + r];
                const float gmb = -logf(-logf(uu));
                s0out[(size_t)bt * RR + r] = sc + gmb;
            }
        }
        __syncthreads();
    }
}

// ===========================================================================
// Subset operator: 2 (b,t) per wave, interleaved chains; exp-domain; DPP+rcp.
// Then per-bt top-K bitonic sort (value desc, index asc).
// ===========================================================================
#define SORT_WRITE(KH, BT) { \
    _Pragma("unroll") \
    for (int t = 0; t < 8; ++t) { \
        const int idx = t * 64 + lane; \
        unsigned long long key = 0ull; \
        if (t < 6 && idx < RR) \
            key = (((unsigned long long)__float_as_uint(KH[t])) << 32) \
                | (unsigned long long)(0xFFFFFFFFu - (unsigned)idx); \
        keys[idx] = key; \
    } \
    __syncthreads(); \
    for (int kk2 = 2; kk2 <= 512; kk2 <<= 1) { \
        for (int jj = kk2 >> 1; jj > 0; jj >>= 1) { \
            _Pragma("unroll") \
            for (int t = 0; t < 8; ++t) { \
                const int i = t * 64 + lane; \
                const int ixj = i ^ jj; \
                if (ixj > i) { \
                    const unsigned long long va = keys[i]; \
                    const unsigned long long vb = keys[ixj]; \
                    const bool sw = ((i & kk2) == 0) ? (va < vb) : (va > vb); \
                    if (sw) { keys[i] = vb; keys[ixj] = va; } \
                } \
            } \
            __syncthreads(); \
        } \
    } \
    for (int k2 = lane; k2 < KSEL; k2 += 64) { \
        const unsigned sidx = 0xFFFFFFFFu - (unsigned)(keys[k2] & 0xFFFFFFFFull); \
        out[PROBN + (size_t)(BT) * KSEL + k2] = (float)sidx; \
    } \
    __syncthreads(); }

__global__ __launch_bounds__(64) void k_subset(
    const float* __restrict__ s0, float* __restrict__ out)
{
    __shared__ unsigned long long keys[512];

    const int btA  = blockIdx.x * 2;
    const int btB  = btA + 1;
    const int lane = threadIdx.x;

    float SA[6], khA[6], SB[6], khB[6];
    #pragma unroll
    for (int i = 0; i < 6; ++i) {
        const int j = i * 64 + lane;
        SA[i]  = (j < RR) ? expf(s0[(size_t)btA * RR + j]) : 0.f;
        SB[i]  = (j < RR) ? expf(s0[(size_t)btB * RR + j]) : 0.f;
        khA[i] = 0.f;
        khB[i] = 0.f;
    }

    for (int it = 0; it < KSEL; ++it) {
        float zA = ((SA[0] + SA[1]) + (SA[2] + SA[3])) + (SA[4] + SA[5]);
        float zB = ((SB[0] + SB[1]) + (SB[2] + SB[3])) + (SB[4] + SB[5]);
        wsum64x2(zA, zB);
        const float invA = __builtin_amdgcn_rcpf(zA);
        const float invB = __builtin_amdgcn_rcpf(zB);
        #pragma unroll
        for (int i = 0; i < 6; ++i) {
            const float ohA = SA[i] * invA;
            khA[i] += ohA;
            SA[i] *= fmaxf(1.f - ohA, 1.17549435e-38f);
            const float ohB = SB[i] * invB;
            khB[i] += ohB;
            SB[i] *= fmaxf(1.f - ohB, 1.17549435e-38f);
        }
    }

    #pragma unroll
    for (int i = 0; i < 6; ++i) {
        const int j = i * 64 + lane;
        if (j < RR) {
            out[(size_t)btA * RR + j] = khA[i];
            out[(size_t)btB * RR + j] = khB[i];
        }
    }

    SORT_WRITE(khA, btA);
    SORT_WRITE(khB, btB);
}

// ===========================================================================
extern "C" void kernel_launch(void* const* d_in, const int* in_sizes, int n_in,
                              void* d_out, int out_size, void* d_ws, size_t ws_size,
                              hipStream_t stream)
{
    const float* x    = (const float*)d_in[0];
    const float* u    = (const float*)d_in[1];
    const float* ln_w = (const float*)d_in[2];
    const float* ln_b = (const float*)d_in[3];
    const float* w1   = (const float*)d_in[4];
    const float* b1   = (const float*)d_in[5];
    const float* w2   = (const float*)d_in[6];
    const float* b2   = (const float*)d_in[7];
    const float* w3   = (const float*)d_in[8];
    const float* b3   = (const float*)d_in[9];

    float* s0  = (float*)d_ws;
    float* out = (float*)d_out;

    const size_t n_local = (size_t)NBT * RR * 64;
    const size_t n_part  = (size_t)NBT * NT * 64;
    const size_t n_gvec  = (size_t)NBT * 32;
    const size_t need    = ((size_t)PROBN + n_local + n_part + n_gvec) * sizeof(float);

    if (ws_size >= need) {
        float* localo = s0 + PROBN;
        float* parto  = localo + n_local;
        float* gvecb  = parto + n_part;
        k_gemm1<<<NBT * NT, 256, 0, stream>>>(x, ln_w, ln_b, w1, b1, localo, parto);
        k_gvec <<<NBT,      64,  0, stream>>>(parto, w2, b2, gvecb);
        k_score<<<NBT * 12, 256, 0, stream>>>(localo, gvecb, w2, w3, b3, u, s0);
    } else {
        k_front<<<NBT, 256, 0, stream>>>(x, u, ln_w, ln_b, w1, b1, w2, b2, w3, b3, s0);
    }
    k_subset<<<NBT / 2, 64, 0, stream>>>(s0, out);
}